// Round 2
// baseline (664.972 us; speedup 1.0000x reference)
//
#include <hip/hip_runtime.h>

// ---------------------------------------------------------------------------
// Generic small-K GEMM: C[rows x NC] = A[rows x K] @ B[K x NC] (+bias)(+=C)(relu)
// B staged entirely in LDS. Each thread: 4 contiguous output cols of one row.
// ---------------------------------------------------------------------------
template <int K, int NC, bool RELU, bool ACCUM>
__global__ __launch_bounds__(256) void gemm_kernel(
    const float* __restrict__ A, const float* __restrict__ B,
    const float* __restrict__ bias, float* __restrict__ C, int nrows) {
  __shared__ float Bs[K * NC];
  for (int i = threadIdx.x; i < K * NC / 4; i += 256) {
    reinterpret_cast<float4*>(Bs)[i] = reinterpret_cast<const float4*>(B)[i];
  }
  __syncthreads();

  constexpr int TPR = NC / 4;     // threads per row
  constexpr int RPB = 256 / TPR;  // rows per block
  const int lane_c = (threadIdx.x % TPR) * 4;
  const long long row = (long long)blockIdx.x * RPB + threadIdx.x / TPR;
  if (row >= nrows) return;

  const float4* A4 = reinterpret_cast<const float4*>(A + row * (long long)K);
  float ax = 0.f, ay = 0.f, az = 0.f, aw = 0.f;
#pragma unroll
  for (int k4 = 0; k4 < K / 4; ++k4) {
    const float4 a = A4[k4];
#pragma unroll
    for (int kk = 0; kk < 4; ++kk) {
      const float av = (kk == 0) ? a.x : (kk == 1) ? a.y : (kk == 2) ? a.z : a.w;
      const float4 b =
          *reinterpret_cast<const float4*>(&Bs[(k4 * 4 + kk) * NC + lane_c]);
      ax = fmaf(av, b.x, ax);
      ay = fmaf(av, b.y, ay);
      az = fmaf(av, b.z, az);
      aw = fmaf(av, b.w, aw);
    }
  }
  if (bias) {
    ax += bias[lane_c + 0];
    ay += bias[lane_c + 1];
    az += bias[lane_c + 2];
    aw += bias[lane_c + 3];
  }
  float* cp = C + row * NC + lane_c;
  if (ACCUM) {
    ax += cp[0]; ay += cp[1]; az += cp[2]; aw += cp[3];
  }
  if (RELU) {
    ax = fmaxf(ax, 0.f); ay = fmaxf(ay, 0.f);
    az = fmaxf(az, 0.f); aw = fmaxf(aw, 0.f);
  }
  float4 out; out.x = ax; out.y = ay; out.z = az; out.w = aw;
  *reinterpret_cast<float4*>(cp) = out;
}

// deg[c] += 1 per edge target (edge index is int32 on device)
__global__ __launch_bounds__(256) void deg_kernel(
    const int* __restrict__ cols, float* __restrict__ deg, int E) {
  const int i = blockIdx.x * 256 + threadIdx.x;
  if (i < E) atomicAdd(&deg[cols[i]], 1.0f);
}

// dis[n] = rsqrt(deg[n] + 1)   (+1 = self loop; always > 0)
__global__ __launch_bounds__(256) void dis_kernel(float* __restrict__ deg, int N) {
  const int i = blockIdx.x * 256 + threadIdx.x;
  if (i < N) deg[i] = rsqrtf(deg[i] + 1.0f);
}

// acc[col[e], d] += h[row[e], d] * dis[row]*dis[col]   (atomic scatter)
template <int D>
__global__ __launch_bounds__(256) void scatter_kernel(
    const float* __restrict__ h, const int* __restrict__ rows,
    const int* __restrict__ cols, const float* __restrict__ dis,
    float* __restrict__ acc, long long E) {
  const long long total = E * D;
  for (long long idx = (long long)blockIdx.x * 256 + threadIdx.x; idx < total;
       idx += (long long)gridDim.x * 256) {
    const long long e = idx / D;
    const int d = (int)(idx - e * D);
    const int r = rows[e];
    const int c = cols[e];
    const float w = dis[r] * dis[c];
    atomicAdd(&acc[(long long)c * D + d], h[(long long)r * D + d] * w);
  }
}

// acc[n,d] += h[n,d]*dis[n]^2 + bias[d]   (self-loop + bias)
template <int D>
__global__ __launch_bounds__(256) void fin_kernel(
    float* __restrict__ acc, const float* __restrict__ h,
    const float* __restrict__ dis, const float* __restrict__ bias, int N) {
  const long long idx = (long long)blockIdx.x * 256 + threadIdx.x;
  if (idx < (long long)N * D) {
    const int n = (int)(idx / D);
    const int d = (int)(idx - (long long)n * D);
    const float ds = dis[n];
    acc[idx] += fmaf(h[idx], ds * ds, bias[d]);
  }
}

extern "C" void kernel_launch(void* const* d_in, const int* in_sizes, int n_in,
                              void* d_out, int out_size, void* d_ws,
                              size_t ws_size, hipStream_t stream) {
  const float* x_self = (const float*)d_in[0];
  const float* x_nb = (const float*)d_in[1];
  const int* ei = (const int*)d_in[2];   // harness delivers integer inputs as int32
  const float* Wis = (const float*)d_in[3];
  const float* bis = (const float*)d_in[4];
  const float* Wos = (const float*)d_in[5];
  const float* bos = (const float*)d_in[6];
  const float* Wg1 = (const float*)d_in[7];
  const float* bg1 = (const float*)d_in[8];
  const float* Wg2 = (const float*)d_in[9];
  const float* bg2 = (const float*)d_in[10];
  const float* Wo = (const float*)d_in[11];
  const float* bo = (const float*)d_in[12];

  const int N = in_sizes[0] / 128;
  const long long E = in_sizes[2] / 2;
  const int* rows = ei;            // sources
  const int* cols = ei + E;        // targets

  float* out1 = (float*)d_out;                 // l1 [N,64]
  float* out2 = out1 + (long long)N * 64;      // x2 [N,64]

  // workspace layout: dis[N] | A[N*128] | B[N*128] | C[N*64]  (51.4 MB)
  float* dis = (float*)d_ws;
  float* bufA = dis + N;
  float* bufB = bufA + (long long)N * 128;
  float* bufC = bufB + (long long)N * 128;

  // --- degrees / norms ---
  hipMemsetAsync(dis, 0, (size_t)N * sizeof(float), stream);
  deg_kernel<<<(int)((E + 255) / 256), 256, 0, stream>>>(cols, dis, (int)E);
  dis_kernel<<<(N + 255) / 256, 256, 0, stream>>>(dis, N);

  // --- self branch: l1 = [x, relu(x@Wis+bis)] @ Wos + bos ---
  gemm_kernel<128, 128, true, false>
      <<<(N + 7) / 8, 256, 0, stream>>>(x_self, Wis, bis, bufA, N);
  gemm_kernel<128, 64, false, false>
      <<<(N + 15) / 16, 256, 0, stream>>>(x_self, Wos, bos, out1, N);
  gemm_kernel<128, 64, false, true>
      <<<(N + 15) / 16, 256, 0, stream>>>(bufA, Wos + 128 * 64, nullptr, out1, N);

  // --- GCN branch ---
  // hg1 = x @ Wg1  (bufA reused)
  gemm_kernel<128, 128, false, false>
      <<<(N + 7) / 8, 256, 0, stream>>>(x_self, Wg1, nullptr, bufA, N);
  // g1 = Agg(hg1) + bg1  -> bufB
  hipMemsetAsync(bufB, 0, (size_t)N * 128 * sizeof(float), stream);
  scatter_kernel<128><<<4096, 256, 0, stream>>>(bufA, rows, cols, dis, bufB, E);
  fin_kernel<128><<<(int)(((long long)N * 128 + 255) / 256), 256, 0, stream>>>(
      bufB, bufA, dis, bg1, N);
  // hg2 = g1 @ Wg2  -> bufC [N,64]
  gemm_kernel<128, 64, false, false>
      <<<(N + 15) / 16, 256, 0, stream>>>(bufB, Wg2, nullptr, bufC, N);
  // g2 = Agg(hg2) + bg2  -> bufA (first N*64 floats)
  hipMemsetAsync(bufA, 0, (size_t)N * 64 * sizeof(float), stream);
  scatter_kernel<64><<<4096, 256, 0, stream>>>(bufC, rows, cols, dis, bufA, E);
  fin_kernel<64><<<(int)(((long long)N * 64 + 255) / 256), 256, 0, stream>>>(
      bufA, bufC, dis, bg2, N);
  // x2 = [x_neighbor, g2] @ Wo + bo
  gemm_kernel<128, 64, false, false>
      <<<(N + 15) / 16, 256, 0, stream>>>(x_nb, Wo, bo, out2, N);
  gemm_kernel<64, 64, false, true>
      <<<(N + 15) / 16, 256, 0, stream>>>(bufA, Wo + 128 * 64, nullptr, out2, N);
}

// Round 3
// 429.447 us; speedup vs baseline: 1.5484x; 1.5484x over previous
//
#include <hip/hip_runtime.h>

// ---------------------------------------------------------------------------
// Generic small-K GEMM: C[rows x NC] = A[rows x K] @ B[K x NC] (+bias)(+=C)(relu)
// B staged entirely in LDS. Each thread: 4 contiguous output cols of one row.
// ---------------------------------------------------------------------------
template <int K, int NC, bool RELU, bool ACCUM>
__global__ __launch_bounds__(256) void gemm_kernel(
    const float* __restrict__ A, const float* __restrict__ B,
    const float* __restrict__ bias, float* __restrict__ C, int nrows) {
  __shared__ float Bs[K * NC];
  for (int i = threadIdx.x; i < K * NC / 4; i += 256) {
    reinterpret_cast<float4*>(Bs)[i] = reinterpret_cast<const float4*>(B)[i];
  }
  __syncthreads();

  constexpr int TPR = NC / 4;     // threads per row
  constexpr int RPB = 256 / TPR;  // rows per block
  const int lane_c = (threadIdx.x % TPR) * 4;
  const long long row = (long long)blockIdx.x * RPB + threadIdx.x / TPR;
  if (row >= nrows) return;

  const float4* A4 = reinterpret_cast<const float4*>(A + row * (long long)K);
  float ax = 0.f, ay = 0.f, az = 0.f, aw = 0.f;
#pragma unroll
  for (int k4 = 0; k4 < K / 4; ++k4) {
    const float4 a = A4[k4];
#pragma unroll
    for (int kk = 0; kk < 4; ++kk) {
      const float av = (kk == 0) ? a.x : (kk == 1) ? a.y : (kk == 2) ? a.z : a.w;
      const float4 b =
          *reinterpret_cast<const float4*>(&Bs[(k4 * 4 + kk) * NC + lane_c]);
      ax = fmaf(av, b.x, ax);
      ay = fmaf(av, b.y, ay);
      az = fmaf(av, b.z, az);
      aw = fmaf(av, b.w, aw);
    }
  }
  if (bias) {
    ax += bias[lane_c + 0];
    ay += bias[lane_c + 1];
    az += bias[lane_c + 2];
    aw += bias[lane_c + 3];
  }
  float* cp = C + row * NC + lane_c;
  if (ACCUM) {
    ax += cp[0]; ay += cp[1]; az += cp[2]; aw += cp[3];
  }
  if (RELU) {
    ax = fmaxf(ax, 0.f); ay = fmaxf(ay, 0.f);
    az = fmaxf(az, 0.f); aw = fmaxf(aw, 0.f);
  }
  float4 out; out.x = ax; out.y = ay; out.z = az; out.w = aw;
  *reinterpret_cast<float4*>(cp) = out;
}

// ---------------------------------------------------------------------------
// CSR build
// ---------------------------------------------------------------------------
__global__ __launch_bounds__(256) void deg_kernel(
    const int* __restrict__ cols, int* __restrict__ deg, int E) {
  const int i = blockIdx.x * 256 + threadIdx.x;
  if (i < E) atomicAdd(&deg[cols[i]], 1);
}

// dis[n] = rsqrt(deg[n] + 1)   (+1 = self loop; always > 0)
__global__ __launch_bounds__(256) void dis_kernel(
    const int* __restrict__ deg, float* __restrict__ dis, int N) {
  const int i = blockIdx.x * 256 + threadIdx.x;
  if (i < N) dis[i] = rsqrtf((float)deg[i] + 1.0f);
}

// single-block exclusive scan: off[i] = sum(deg[0..i)), off[N] = E
__global__ __launch_bounds__(1024) void scan_kernel(
    const int* __restrict__ deg, int* __restrict__ off, int N) {
  __shared__ int sdata[1024];
  const int tid = threadIdx.x;
  int carry = 0;
  for (int base = 0; base <= N; base += 1024) {
    const int i = base + tid;
    const int v = (i < N) ? deg[i] : 0;
    sdata[tid] = v;
    __syncthreads();
    for (int o = 1; o < 1024; o <<= 1) {
      const int t = (tid >= o) ? sdata[tid - o] : 0;
      __syncthreads();
      sdata[tid] += t;
      __syncthreads();
    }
    if (i <= N) off[i] = carry + sdata[tid] - v;
    carry += sdata[1023];
    __syncthreads();
  }
}

// csr_src[pos] = row, bucketed by col. NOTE: shifts off[] so that after this
// kernel, off[c] = END of segment c (start of c is off[c-1], or 0 for c=0).
__global__ __launch_bounds__(256) void fill_kernel(
    const int* __restrict__ rows, const int* __restrict__ cols,
    int* __restrict__ off, int* __restrict__ csr_src, int E) {
  const int i = blockIdx.x * 256 + threadIdx.x;
  if (i < E) {
    const int pos = atomicAdd(&off[cols[i]], 1);
    csr_src[pos] = rows[i];
  }
}

// ---------------------------------------------------------------------------
// CSR gather: out[n] = sum_{e: col=n} h[src_e]*dis[src]*dis[n]
//                      + h[n]*dis[n]^2 + bias        (one wave per node)
// ---------------------------------------------------------------------------
template <int D>
__global__ __launch_bounds__(256) void gather_kernel(
    const float* __restrict__ h, const int* __restrict__ csr_src,
    const int* __restrict__ off, const float* __restrict__ dis,
    const float* __restrict__ bias, float* __restrict__ out, int N) {
  const int wid = (blockIdx.x * 256 + threadIdx.x) >> 6;
  const int lane = threadIdx.x & 63;
  if (wid >= N) return;
  const int n = wid;
  const float dn = dis[n];

  constexpr int VPL = D / 64;  // floats per lane (2 for D=128, 1 for D=64)
  const int coff = lane * VPL;

  float acc[VPL];
  {  // self loop
    const float w = dn * dn;
    const float* hn = h + (long long)n * D + coff;
#pragma unroll
    for (int v = 0; v < VPL; ++v) acc[v] = hn[v] * w;
  }

  const int start = (n == 0) ? 0 : off[n - 1];
  const int end = off[n];
  int j = start;
  for (; j + 1 < end; j += 2) {
    const int r0 = csr_src[j];
    const int r1 = csr_src[j + 1];
    const float w0 = dis[r0] * dn;
    const float w1 = dis[r1] * dn;
    const float* h0 = h + (long long)r0 * D + coff;
    const float* h1 = h + (long long)r1 * D + coff;
#pragma unroll
    for (int v = 0; v < VPL; ++v) {
      const float a0 = h0[v];
      const float a1 = h1[v];
      acc[v] = fmaf(a0, w0, acc[v]);
      acc[v] = fmaf(a1, w1, acc[v]);
    }
  }
  if (j < end) {
    const int r0 = csr_src[j];
    const float w0 = dis[r0] * dn;
    const float* h0 = h + (long long)r0 * D + coff;
#pragma unroll
    for (int v = 0; v < VPL; ++v) acc[v] = fmaf(h0[v], w0, acc[v]);
  }

  float* op = out + (long long)n * D + coff;
#pragma unroll
  for (int v = 0; v < VPL; ++v) op[v] = acc[v] + bias[coff + v];
}

extern "C" void kernel_launch(void* const* d_in, const int* in_sizes, int n_in,
                              void* d_out, int out_size, void* d_ws,
                              size_t ws_size, hipStream_t stream) {
  const float* x_self = (const float*)d_in[0];
  const float* x_nb = (const float*)d_in[1];
  const int* ei = (const int*)d_in[2];  // int32 on device
  const float* Wis = (const float*)d_in[3];
  const float* bis = (const float*)d_in[4];
  const float* Wos = (const float*)d_in[5];
  const float* bos = (const float*)d_in[6];
  const float* Wg1 = (const float*)d_in[7];
  const float* bg1 = (const float*)d_in[8];
  const float* Wg2 = (const float*)d_in[9];
  const float* bg2 = (const float*)d_in[10];
  const float* Wo = (const float*)d_in[11];
  const float* bo = (const float*)d_in[12];

  const int N = in_sizes[0] / 128;
  const int E = (int)(in_sizes[2] / 2);
  const int* rows = ei;      // sources
  const int* cols = ei + E;  // targets

  float* out1 = (float*)d_out;             // l1 [N,64]
  float* out2 = out1 + (long long)N * 64;  // x2 [N,64]

  // ws layout (4B units): dis[N] | deg[N] | off[N+1] | csr_src[E]
  //                       | bufA[N*128] | bufB[N*128] | bufC[N*64]   (~54 MB)
  float* dis = (float*)d_ws;
  int* deg = (int*)(dis + N);
  int* off = deg + N;
  int* csr_src = off + N + 1;
  float* bufA = (float*)(csr_src + E);
  float* bufB = bufA + (long long)N * 128;
  float* bufC = bufB + (long long)N * 128;

  // --- CSR build + norms ---
  hipMemsetAsync(deg, 0, (size_t)N * sizeof(int), stream);
  deg_kernel<<<(E + 255) / 256, 256, 0, stream>>>(cols, deg, E);
  dis_kernel<<<(N + 255) / 256, 256, 0, stream>>>(deg, dis, N);
  scan_kernel<<<1, 1024, 0, stream>>>(deg, off, N);
  fill_kernel<<<(E + 255) / 256, 256, 0, stream>>>(rows, cols, off, csr_src, E);

  // --- self branch: l1 = [x, relu(x@Wis+bis)] @ Wos + bos ---
  gemm_kernel<128, 128, true, false>
      <<<(N + 7) / 8, 256, 0, stream>>>(x_self, Wis, bis, bufA, N);
  gemm_kernel<128, 64, false, false>
      <<<(N + 15) / 16, 256, 0, stream>>>(x_self, Wos, bos, out1, N);
  gemm_kernel<128, 64, false, true>
      <<<(N + 15) / 16, 256, 0, stream>>>(bufA, Wos + 128 * 64, nullptr, out1, N);

  // --- GCN branch ---
  gemm_kernel<128, 128, false, false>
      <<<(N + 7) / 8, 256, 0, stream>>>(x_self, Wg1, nullptr, bufA, N);
  gather_kernel<128><<<(N + 3) / 4, 256, 0, stream>>>(
      bufA, csr_src, off, dis, bg1, bufB, N);
  gemm_kernel<128, 64, false, false>
      <<<(N + 15) / 16, 256, 0, stream>>>(bufB, Wg2, nullptr, bufC, N);
  gather_kernel<64><<<(N + 3) / 4, 256, 0, stream>>>(
      bufC, csr_src, off, dis, bg2, bufA, N);
  gemm_kernel<128, 64, false, false>
      <<<(N + 15) / 16, 256, 0, stream>>>(x_nb, Wo, bo, out2, N);
  gemm_kernel<64, 64, false, true>
      <<<(N + 15) / 16, 256, 0, stream>>>(bufA, Wo + 128 * 64, nullptr, out2, N);
}

// Round 4
// 373.454 us; speedup vs baseline: 1.7806x; 1.1499x over previous
//
#include <hip/hip_runtime.h>

// ---------------------------------------------------------------------------
// Small-K GEMM: C[rows x NC] = A[rows x K] @ B[K x NC] (+bias)(+=C)(relu)
// B staged in LDS. Each thread: ROWS rows x 4 contiguous cols (register block)
// -> one LDS B-read feeds ROWS FMA chains; ROWS independent A-load streams.
// ---------------------------------------------------------------------------
template <int K, int NC, bool RELU, bool ACCUM, int ROWS>
__global__ __launch_bounds__(256) void gemm_kernel(
    const float* __restrict__ A, const float* __restrict__ B,
    const float* __restrict__ bias, float* __restrict__ C, int nrows) {
  __shared__ float Bs[K * NC];
  for (int i = threadIdx.x; i < K * NC / 4; i += 256) {
    reinterpret_cast<float4*>(Bs)[i] = reinterpret_cast<const float4*>(B)[i];
  }
  __syncthreads();

  constexpr int TPR = NC / 4;              // threads per row
  constexpr int RPB = (256 / TPR) * ROWS;  // rows per block
  const int lane_c = (threadIdx.x % TPR) * 4;
  const long long row0 =
      (long long)blockIdx.x * RPB + (threadIdx.x / TPR) * ROWS;
  if (row0 >= nrows) return;
  const bool full = (row0 + ROWS <= nrows);

  const float* Ap = A + row0 * K;
  float acc[ROWS][4] = {};

  if (full) {
#pragma unroll 2
    for (int k4 = 0; k4 < K / 4; ++k4) {
      float4 a[ROWS];
#pragma unroll
      for (int r = 0; r < ROWS; ++r)
        a[r] = *reinterpret_cast<const float4*>(Ap + (long long)r * K + k4 * 4);
#pragma unroll
      for (int kk = 0; kk < 4; ++kk) {
        const float4 b =
            *reinterpret_cast<const float4*>(&Bs[(k4 * 4 + kk) * NC + lane_c]);
#pragma unroll
        for (int r = 0; r < ROWS; ++r) {
          const float av =
              (kk == 0) ? a[r].x : (kk == 1) ? a[r].y : (kk == 2) ? a[r].z : a[r].w;
          acc[r][0] = fmaf(av, b.x, acc[r][0]);
          acc[r][1] = fmaf(av, b.y, acc[r][1]);
          acc[r][2] = fmaf(av, b.z, acc[r][2]);
          acc[r][3] = fmaf(av, b.w, acc[r][3]);
        }
      }
    }
  } else {
    for (int r = 0; r < ROWS; ++r) {
      if (row0 + r >= nrows) break;
      for (int k4 = 0; k4 < K / 4; ++k4) {
        const float4 a =
            *reinterpret_cast<const float4*>(Ap + (long long)r * K + k4 * 4);
#pragma unroll
        for (int kk = 0; kk < 4; ++kk) {
          const float4 b = *reinterpret_cast<const float4*>(
              &Bs[(k4 * 4 + kk) * NC + lane_c]);
          const float av =
              (kk == 0) ? a.x : (kk == 1) ? a.y : (kk == 2) ? a.z : a.w;
          acc[r][0] = fmaf(av, b.x, acc[r][0]);
          acc[r][1] = fmaf(av, b.y, acc[r][1]);
          acc[r][2] = fmaf(av, b.z, acc[r][2]);
          acc[r][3] = fmaf(av, b.w, acc[r][3]);
        }
      }
    }
  }

#pragma unroll
  for (int r = 0; r < ROWS; ++r) {
    const long long row = row0 + r;
    if (row >= nrows) break;
    float ax = acc[r][0], ay = acc[r][1], az = acc[r][2], aw = acc[r][3];
    if (bias) {
      ax += bias[lane_c + 0];
      ay += bias[lane_c + 1];
      az += bias[lane_c + 2];
      aw += bias[lane_c + 3];
    }
    float* cp = C + row * NC + lane_c;
    if (ACCUM) {
      ax += cp[0]; ay += cp[1]; az += cp[2]; aw += cp[3];
    }
    if (RELU) {
      ax = fmaxf(ax, 0.f); ay = fmaxf(ay, 0.f);
      az = fmaxf(az, 0.f); aw = fmaxf(aw, 0.f);
    }
    float4 out; out.x = ax; out.y = ay; out.z = az; out.w = aw;
    *reinterpret_cast<float4*>(cp) = out;
  }
}

// ---------------------------------------------------------------------------
// CSR build
// ---------------------------------------------------------------------------
__global__ __launch_bounds__(256) void deg_kernel(
    const int* __restrict__ cols, int* __restrict__ deg, int E) {
  const int i = blockIdx.x * 256 + threadIdx.x;
  if (i < E) atomicAdd(&deg[cols[i]], 1);
}

// dis[n] = rsqrt(deg[n] + 1)   (+1 = self loop; always > 0)
__global__ __launch_bounds__(256) void dis_kernel(
    const int* __restrict__ deg, float* __restrict__ dis, int N) {
  const int i = blockIdx.x * 256 + threadIdx.x;
  if (i < N) dis[i] = rsqrtf((float)deg[i] + 1.0f);
}

// hierarchical exclusive scan: scan1 (per-block) -> scan2 (partials) -> scan3
__global__ __launch_bounds__(1024) void scan1_kernel(
    const int* __restrict__ deg, int* __restrict__ off, int* __restrict__ part,
    int N) {
  __shared__ int s[1024];
  const int tid = threadIdx.x;
  const int i = blockIdx.x * 1024 + tid;
  const int v = (i < N) ? deg[i] : 0;
  s[tid] = v;
  __syncthreads();
  for (int o = 1; o < 1024; o <<= 1) {
    const int t = (tid >= o) ? s[tid - o] : 0;
    __syncthreads();
    s[tid] += t;
    __syncthreads();
  }
  if (i < N) off[i] = s[tid] - v;  // exclusive within block
  if (tid == 1023) part[blockIdx.x] = s[1023];
}

__global__ __launch_bounds__(1024) void scan2_kernel(int* __restrict__ part,
                                                     int P) {
  __shared__ int s[1024];
  const int tid = threadIdx.x;
  const int v = (tid < P) ? part[tid] : 0;
  s[tid] = v;
  __syncthreads();
  for (int o = 1; o < 1024; o <<= 1) {
    const int t = (tid >= o) ? s[tid - o] : 0;
    __syncthreads();
    s[tid] += t;
    __syncthreads();
  }
  if (tid < P) part[tid] = s[tid] - v;  // exclusive block offsets
}

__global__ __launch_bounds__(1024) void scan3_kernel(
    int* __restrict__ off, const int* __restrict__ part, int N) {
  const int i = blockIdx.x * 1024 + threadIdx.x;
  if (i < N) off[i] += part[blockIdx.x];
}

// csr_src[pos] = row, bucketed by col. Shifts off[] so that afterwards
// off[c] = END of segment c (start of c is off[c-1], or 0 for c=0).
__global__ __launch_bounds__(256) void fill_kernel(
    const int* __restrict__ rows, const int* __restrict__ cols,
    int* __restrict__ off, int* __restrict__ csr_src, int E) {
  const int i = blockIdx.x * 256 + threadIdx.x;
  if (i < E) {
    const int pos = atomicAdd(&off[cols[i]], 1);
    csr_src[pos] = rows[i];
  }
}

// ---------------------------------------------------------------------------
// CSR gather: out[n] = sum_{e: col=n} h[src_e]*dis[src]*dis[n]
//                      + h[n]*dis[n]^2 + bias        (one wave per node)
// ---------------------------------------------------------------------------
template <int D>
__global__ __launch_bounds__(256) void gather_kernel(
    const float* __restrict__ h, const int* __restrict__ csr_src,
    const int* __restrict__ off, const float* __restrict__ dis,
    const float* __restrict__ bias, float* __restrict__ out, int N) {
  const int wid = (blockIdx.x * 256 + threadIdx.x) >> 6;
  const int lane = threadIdx.x & 63;
  if (wid >= N) return;
  const int n = wid;
  const float dn = dis[n];

  constexpr int VPL = D / 64;  // floats per lane
  const int coff = lane * VPL;

  float acc[VPL];
  {  // self loop
    const float w = dn * dn;
    const float* hn = h + (long long)n * D + coff;
#pragma unroll
    for (int v = 0; v < VPL; ++v) acc[v] = hn[v] * w;
  }

  const int start = (n == 0) ? 0 : off[n - 1];
  const int end = off[n];
  int j = start;
  for (; j + 1 < end; j += 2) {
    const int r0 = csr_src[j];
    const int r1 = csr_src[j + 1];
    const float w0 = dis[r0] * dn;
    const float w1 = dis[r1] * dn;
    const float* h0 = h + (long long)r0 * D + coff;
    const float* h1 = h + (long long)r1 * D + coff;
#pragma unroll
    for (int v = 0; v < VPL; ++v) {
      const float a0 = h0[v];
      const float a1 = h1[v];
      acc[v] = fmaf(a0, w0, acc[v]);
      acc[v] = fmaf(a1, w1, acc[v]);
    }
  }
  if (j < end) {
    const int r0 = csr_src[j];
    const float w0 = dis[r0] * dn;
    const float* h0 = h + (long long)r0 * D + coff;
#pragma unroll
    for (int v = 0; v < VPL; ++v) acc[v] = fmaf(h0[v], w0, acc[v]);
  }

  float* op = out + (long long)n * D + coff;
#pragma unroll
  for (int v = 0; v < VPL; ++v) op[v] = acc[v] + bias[coff + v];
}

extern "C" void kernel_launch(void* const* d_in, const int* in_sizes, int n_in,
                              void* d_out, int out_size, void* d_ws,
                              size_t ws_size, hipStream_t stream) {
  const float* x_self = (const float*)d_in[0];
  const float* x_nb = (const float*)d_in[1];
  const int* ei = (const int*)d_in[2];  // int32 on device
  const float* Wis = (const float*)d_in[3];
  const float* bis = (const float*)d_in[4];
  const float* Wos = (const float*)d_in[5];
  const float* bos = (const float*)d_in[6];
  const float* Wg1 = (const float*)d_in[7];
  const float* bg1 = (const float*)d_in[8];
  const float* Wg2 = (const float*)d_in[9];
  const float* bg2 = (const float*)d_in[10];
  const float* Wo = (const float*)d_in[11];
  const float* bo = (const float*)d_in[12];

  const int N = in_sizes[0] / 128;
  const int E = (int)(in_sizes[2] / 2);
  const int* rows = ei;      // sources
  const int* cols = ei + E;  // targets

  float* out1 = (float*)d_out;             // l1 [N,64]
  float* out2 = out1 + (long long)N * 64;  // x2 [N,64]

  // ws layout (4B units): dis[N] | deg[N] | off[N+1] | part[64] | csr_src[E]
  //                       | bufA[N*128] | bufB[N*128] | bufC[N*64]
  float* dis = (float*)d_ws;
  int* deg = (int*)(dis + N);
  int* off = deg + N;
  int* part = off + N + 1;
  int* csr_src = part + 64;
  float* bufA = (float*)(csr_src + E);
  float* bufB = bufA + (long long)N * 128;
  float* bufC = bufB + (long long)N * 128;

  const int NB = (N + 1023) / 1024;  // scan blocks (40)

  // --- CSR build + norms ---
  hipMemsetAsync(deg, 0, (size_t)N * sizeof(int), stream);
  deg_kernel<<<(E + 255) / 256, 256, 0, stream>>>(cols, deg, E);
  dis_kernel<<<(N + 255) / 256, 256, 0, stream>>>(deg, dis, N);
  scan1_kernel<<<NB, 1024, 0, stream>>>(deg, off, part, N);
  scan2_kernel<<<1, 1024, 0, stream>>>(part, NB);
  scan3_kernel<<<NB, 1024, 0, stream>>>(off, part, N);
  fill_kernel<<<(E + 255) / 256, 256, 0, stream>>>(rows, cols, off, csr_src, E);

  // --- self branch: l1 = [x, relu(x@Wis+bis)] @ Wos + bos ---
  gemm_kernel<128, 128, true, false, 4>
      <<<(N + 31) / 32, 256, 0, stream>>>(x_self, Wis, bis, bufA, N);
  gemm_kernel<128, 64, false, false, 2>
      <<<(N + 31) / 32, 256, 0, stream>>>(x_self, Wos, bos, out1, N);
  gemm_kernel<128, 64, false, true, 2>
      <<<(N + 31) / 32, 256, 0, stream>>>(bufA, Wos + 128 * 64, nullptr, out1, N);

  // --- GCN branch ---
  gemm_kernel<128, 128, false, false, 4>
      <<<(N + 31) / 32, 256, 0, stream>>>(x_self, Wg1, nullptr, bufA, N);
  gather_kernel<128><<<(N + 3) / 4, 256, 0, stream>>>(
      bufA, csr_src, off, dis, bg1, bufB, N);
  gemm_kernel<128, 64, false, false, 2>
      <<<(N + 31) / 32, 256, 0, stream>>>(bufB, Wg2, nullptr, bufC, N);
  gather_kernel<64><<<(N + 3) / 4, 256, 0, stream>>>(
      bufC, csr_src, off, dis, bg2, bufA, N);
  gemm_kernel<128, 64, false, false, 2>
      <<<(N + 31) / 32, 256, 0, stream>>>(x_nb, Wo, bo, out2, N);
  gemm_kernel<64, 64, false, true, 2>
      <<<(N + 31) / 32, 256, 0, stream>>>(bufA, Wo + 128 * 64, nullptr, out2, N);
}

// Round 5
// 247.742 us; speedup vs baseline: 2.6841x; 1.5074x over previous
//
#include <hip/hip_runtime.h>

typedef short s8v __attribute__((ext_vector_type(8)));
typedef float f4v __attribute__((ext_vector_type(4)));

__device__ __forceinline__ unsigned short f2bf(float f) {
  unsigned u = __float_as_uint(f);
  u = (u + 0x7fffu + ((u >> 16) & 1u)) >> 16;
  return (unsigned short)u;
}
__device__ __forceinline__ float bf2f(unsigned short s) {
  return __uint_as_float(((unsigned)s) << 16);
}

// ---------------------------------------------------------------------------
// f32 -> bf16 convert, 4 elems/thread
// ---------------------------------------------------------------------------
__global__ __launch_bounds__(256) void cvt_kernel(
    const float* __restrict__ in, unsigned short* __restrict__ out, int n4) {
  const int i = blockIdx.x * 256 + threadIdx.x;
  if (i >= n4) return;
  const float4 v = reinterpret_cast<const float4*>(in)[i];
  ushort4 o;
  o.x = f2bf(v.x); o.y = f2bf(v.y); o.z = f2bf(v.z); o.w = f2bf(v.w);
  reinterpret_cast<ushort4*>(out)[i] = o;
}

// ---------------------------------------------------------------------------
// Pack W[K][NC] (f32, row-major) into MFMA B-fragment order:
// P[((kc*(NC/16)+ct)*64 + lane)*8 + j] = bf16( W[kc*32+(lane>>4)*8+j][ct*16+(lane&15)] )
// ---------------------------------------------------------------------------
template <int K, int NC>
__global__ __launch_bounds__(256) void pack_kernel(
    const float* __restrict__ W, unsigned short* __restrict__ P) {
  constexpr int total = (K / 32) * (NC / 16) * 64;
  const int t = blockIdx.x * 256 + threadIdx.x;
  if (t >= total) return;
  const int lane = t & 63;
  const int ct = (t >> 6) % (NC / 16);
  const int kc = (t >> 6) / (NC / 16);
  const int col = ct * 16 + (lane & 15);
  const int krow = kc * 32 + (lane >> 4) * 8;
  unsigned short tmp[8];
#pragma unroll
  for (int j = 0; j < 8; ++j) tmp[j] = f2bf(W[(krow + j) * NC + col]);
  uint4 o;
  o.x = (unsigned)tmp[0] | ((unsigned)tmp[1] << 16);
  o.y = (unsigned)tmp[2] | ((unsigned)tmp[3] << 16);
  o.z = (unsigned)tmp[4] | ((unsigned)tmp[5] << 16);
  o.w = (unsigned)tmp[6] | ((unsigned)tmp[7] << 16);
  reinterpret_cast<uint4*>(P)[t] = o;
}

// ---------------------------------------------------------------------------
// MFMA GEMM: C = A1[M x K1] @ B1 + (A2[M x K2] @ B2) + bias, optional relu.
// A* are bf16 row-major; B* are pre-packed fragment-order bf16 (staged in LDS).
// Block = 4 waves, each wave computes 16 rows x NC. M must be % 64 == 0.
// k-consistency: A-frag elem (group g, j) holds A[row][kc*32+g*8+j] and B-frag
// elem (g,j) holds B[kc*32+g*8+j][col] -> products pair correctly regardless
// of the HW's internal k mapping. C/D mapping per m89: col=lane&15,
// row=(lane>>4)*4+reg.
// ---------------------------------------------------------------------------
template <int K1, int K2, int NC, bool RELU, bool OUT_BF16>
__global__ __launch_bounds__(256) void mfma_gemm_kernel(
    const unsigned short* __restrict__ A1, const unsigned short* __restrict__ A2,
    const unsigned short* __restrict__ P1, const unsigned short* __restrict__ P2,
    const float* __restrict__ bias, void* __restrict__ Cout) {
  constexpr int NT = NC / 16;
  constexpr int KC1 = K1 / 32;
  constexpr int KC2 = (K2 > 0) ? (K2 / 32) : 1;  // array-size guard
  __shared__ unsigned short Bs[(K1 + K2) * NC];

  {
    uint4* d = reinterpret_cast<uint4*>(Bs);
    constexpr int n1 = K1 * NC / 8;
    const uint4* s1 = reinterpret_cast<const uint4*>(P1);
    for (int i = threadIdx.x; i < n1; i += 256) d[i] = s1[i];
    if constexpr (K2 > 0) {
      constexpr int n2 = K2 * NC / 8;
      const uint4* s2 = reinterpret_cast<const uint4*>(P2);
      for (int i = threadIdx.x; i < n2; i += 256) d[n1 + i] = s2[i];
    }
  }

  const int wave = threadIdx.x >> 6;
  const int lane = threadIdx.x & 63;
  const int row0 = blockIdx.x * 64 + wave * 16;
  const int arow = row0 + (lane & 15);
  const int koff = (lane >> 4) * 8;

  // preload all A fragments (independent global loads)
  s8v a1[KC1];
#pragma unroll
  for (int kc = 0; kc < KC1; ++kc)
    a1[kc] = *reinterpret_cast<const s8v*>(A1 + (long long)arow * K1 + kc * 32 + koff);
  s8v a2[KC2];
  if constexpr (K2 > 0) {
#pragma unroll
    for (int kc = 0; kc < K2 / 32; ++kc)
      a2[kc] = *reinterpret_cast<const s8v*>(A2 + (long long)arow * K2 + kc * 32 + koff);
  }

  __syncthreads();

  f4v acc[NT] = {};
#pragma unroll
  for (int kc = 0; kc < KC1; ++kc) {
#pragma unroll
    for (int ct = 0; ct < NT; ++ct) {
      const s8v b =
          *reinterpret_cast<const s8v*>(&Bs[((kc * NT + ct) * 64 + lane) * 8]);
      acc[ct] = __builtin_amdgcn_mfma_f32_16x16x32_bf16(a1[kc], b, acc[ct], 0, 0, 0);
    }
  }
  if constexpr (K2 > 0) {
#pragma unroll
    for (int kc = 0; kc < K2 / 32; ++kc) {
#pragma unroll
      for (int ct = 0; ct < NT; ++ct) {
        const s8v b = *reinterpret_cast<const s8v*>(
            &Bs[(((KC1 + kc) * NT + ct) * 64 + lane) * 8]);
        acc[ct] = __builtin_amdgcn_mfma_f32_16x16x32_bf16(a2[kc], b, acc[ct], 0, 0, 0);
      }
    }
  }

  const int crow0 = row0 + (lane >> 4) * 4;
  const int ccol = lane & 15;
#pragma unroll
  for (int ct = 0; ct < NT; ++ct) {
    const int col = ct * 16 + ccol;
    const float bv = bias ? bias[col] : 0.f;
#pragma unroll
    for (int r = 0; r < 4; ++r) {
      float v = acc[ct][r] + bv;
      if (RELU) v = fmaxf(v, 0.f);
      const long long idx = (long long)(crow0 + r) * NC + col;
      if (OUT_BF16)
        ((unsigned short*)Cout)[idx] = f2bf(v);
      else
        ((float*)Cout)[idx] = v;
    }
  }
}

// ---------------------------------------------------------------------------
// CSR build
// ---------------------------------------------------------------------------
__global__ __launch_bounds__(256) void deg_kernel(
    const int* __restrict__ cols, int* __restrict__ deg, int E) {
  const int i = blockIdx.x * 256 + threadIdx.x;
  if (i < E) atomicAdd(&deg[cols[i]], 1);
}

__global__ __launch_bounds__(256) void dis_kernel(
    const int* __restrict__ deg, float* __restrict__ dis, int N) {
  const int i = blockIdx.x * 256 + threadIdx.x;
  if (i < N) dis[i] = rsqrtf((float)deg[i] + 1.0f);
}

__global__ __launch_bounds__(1024) void scan1_kernel(
    const int* __restrict__ deg, int* __restrict__ off, int* __restrict__ part,
    int N) {
  __shared__ int s[1024];
  const int tid = threadIdx.x;
  const int i = blockIdx.x * 1024 + tid;
  const int v = (i < N) ? deg[i] : 0;
  s[tid] = v;
  __syncthreads();
  for (int o = 1; o < 1024; o <<= 1) {
    const int t = (tid >= o) ? s[tid - o] : 0;
    __syncthreads();
    s[tid] += t;
    __syncthreads();
  }
  if (i < N) off[i] = s[tid] - v;
  if (tid == 1023) part[blockIdx.x] = s[1023];
}

__global__ __launch_bounds__(1024) void scan2_kernel(int* __restrict__ part, int P) {
  __shared__ int s[1024];
  const int tid = threadIdx.x;
  const int v = (tid < P) ? part[tid] : 0;
  s[tid] = v;
  __syncthreads();
  for (int o = 1; o < 1024; o <<= 1) {
    const int t = (tid >= o) ? s[tid - o] : 0;
    __syncthreads();
    s[tid] += t;
    __syncthreads();
  }
  if (tid < P) part[tid] = s[tid] - v;
}

__global__ __launch_bounds__(1024) void scan3_kernel(
    int* __restrict__ off, const int* __restrict__ part, int N) {
  const int i = blockIdx.x * 1024 + threadIdx.x;
  if (i < N) off[i] += part[blockIdx.x];
}

// after this kernel off[c] = END of segment c (start = off[c-1] or 0)
__global__ __launch_bounds__(256) void fill_kernel(
    const int* __restrict__ rows, const int* __restrict__ cols,
    int* __restrict__ off, int* __restrict__ csr_src, int E) {
  const int i = blockIdx.x * 256 + threadIdx.x;
  if (i < E) {
    const int pos = atomicAdd(&off[cols[i]], 1);
    csr_src[pos] = rows[i];
  }
}

// ---------------------------------------------------------------------------
// CSR gathers on bf16 h, f32 accumulate, bf16 out (one wave per node)
// ---------------------------------------------------------------------------
__global__ __launch_bounds__(256) void gather128_kernel(
    const unsigned short* __restrict__ h, const int* __restrict__ csr_src,
    const int* __restrict__ off, const float* __restrict__ dis,
    const float* __restrict__ bias, unsigned short* __restrict__ out, int N) {
  const int n = (blockIdx.x * 256 + threadIdx.x) >> 6;
  const int lane = threadIdx.x & 63;
  if (n >= N) return;
  const float dn = dis[n];
  const unsigned* h32 = reinterpret_cast<const unsigned*>(h);
  const unsigned us = h32[(long long)n * 64 + lane];
  float a0 = __uint_as_float(us << 16) * (dn * dn);
  float a1 = __uint_as_float(us & 0xffff0000u) * (dn * dn);
  const int start = (n == 0) ? 0 : off[n - 1];
  const int end = off[n];
  int j = start;
  for (; j + 1 < end; j += 2) {
    const int r0 = csr_src[j], r1 = csr_src[j + 1];
    const float w0 = dis[r0] * dn, w1 = dis[r1] * dn;
    const unsigned u0 = h32[(long long)r0 * 64 + lane];
    const unsigned u1 = h32[(long long)r1 * 64 + lane];
    a0 = fmaf(__uint_as_float(u0 << 16), w0, a0);
    a1 = fmaf(__uint_as_float(u0 & 0xffff0000u), w0, a1);
    a0 = fmaf(__uint_as_float(u1 << 16), w1, a0);
    a1 = fmaf(__uint_as_float(u1 & 0xffff0000u), w1, a1);
  }
  if (j < end) {
    const int r0 = csr_src[j];
    const float w0 = dis[r0] * dn;
    const unsigned u0 = h32[(long long)r0 * 64 + lane];
    a0 = fmaf(__uint_as_float(u0 << 16), w0, a0);
    a1 = fmaf(__uint_as_float(u0 & 0xffff0000u), w0, a1);
  }
  a0 += bias[lane * 2];
  a1 += bias[lane * 2 + 1];
  reinterpret_cast<unsigned*>(out)[(long long)n * 64 + lane] =
      (unsigned)f2bf(a0) | ((unsigned)f2bf(a1) << 16);
}

__global__ __launch_bounds__(256) void gather64_kernel(
    const unsigned short* __restrict__ h, const int* __restrict__ csr_src,
    const int* __restrict__ off, const float* __restrict__ dis,
    const float* __restrict__ bias, unsigned short* __restrict__ out, int N) {
  const int n = (blockIdx.x * 256 + threadIdx.x) >> 6;
  const int lane = threadIdx.x & 63;
  if (n >= N) return;
  const float dn = dis[n];
  float a0 = bf2f(h[(long long)n * 64 + lane]) * (dn * dn);
  const int start = (n == 0) ? 0 : off[n - 1];
  const int end = off[n];
  int j = start;
  for (; j + 1 < end; j += 2) {
    const int r0 = csr_src[j], r1 = csr_src[j + 1];
    const float w0 = dis[r0] * dn, w1 = dis[r1] * dn;
    const float v0 = bf2f(h[(long long)r0 * 64 + lane]);
    const float v1 = bf2f(h[(long long)r1 * 64 + lane]);
    a0 = fmaf(v0, w0, a0);
    a0 = fmaf(v1, w1, a0);
  }
  if (j < end) {
    const int r0 = csr_src[j];
    a0 = fmaf(bf2f(h[(long long)r0 * 64 + lane]), dis[r0] * dn, a0);
  }
  out[(long long)n * 64 + lane] = f2bf(a0 + bias[lane]);
}

extern "C" void kernel_launch(void* const* d_in, const int* in_sizes, int n_in,
                              void* d_out, int out_size, void* d_ws,
                              size_t ws_size, hipStream_t stream) {
  const float* x_self = (const float*)d_in[0];
  const float* x_nb = (const float*)d_in[1];
  const int* ei = (const int*)d_in[2];
  const float* Wis = (const float*)d_in[3];
  const float* bis = (const float*)d_in[4];
  const float* Wos = (const float*)d_in[5];
  const float* bos = (const float*)d_in[6];
  const float* Wg1 = (const float*)d_in[7];
  const float* bg1 = (const float*)d_in[8];
  const float* Wg2 = (const float*)d_in[9];
  const float* bg2 = (const float*)d_in[10];
  const float* Wo = (const float*)d_in[11];
  const float* bo = (const float*)d_in[12];

  const int N = in_sizes[0] / 128;
  const int E = (int)(in_sizes[2] / 2);
  const int* rows = ei;
  const int* cols = ei + E;

  float* out1 = (float*)d_out;
  float* out2 = out1 + (long long)N * 64;

  // ws layout: dis[N] f32 | deg[N] | off[N+16] | part[64] | csr[E] |
  //            S1[N*128] bf16 | S2[N*128] bf16 | packed weights
  float* dis = (float*)d_ws;
  int* deg = (int*)(dis + N);
  int* off = deg + N;
  int* part = off + N + 16;
  int* csr_src = part + 64;
  unsigned short* S1 = (unsigned short*)(csr_src + E);
  unsigned short* S2 = S1 + (long long)N * 128;
  unsigned short* pWis = S2 + (long long)N * 128;   // 128x128
  unsigned short* pWg1 = pWis + 128 * 128;          // 128x128
  unsigned short* pWos0 = pWg1 + 128 * 128;         // 128x64
  unsigned short* pWos1 = pWos0 + 128 * 64;         // 128x64
  unsigned short* pWg2 = pWos1 + 128 * 64;          // 128x64
  unsigned short* pWo0 = pWg2 + 128 * 64;           // 128x64
  unsigned short* pWo1 = pWo0 + 128 * 64;           // 64x64

  const int NB = (N + 1023) / 1024;

  // --- CSR build + norms ---
  hipMemsetAsync(deg, 0, (size_t)N * sizeof(int), stream);
  deg_kernel<<<(E + 255) / 256, 256, 0, stream>>>(cols, deg, E);
  dis_kernel<<<(N + 255) / 256, 256, 0, stream>>>(deg, dis, N);
  scan1_kernel<<<NB, 1024, 0, stream>>>(deg, off, part, N);
  scan2_kernel<<<1, 1024, 0, stream>>>(part, NB);
  scan3_kernel<<<NB, 1024, 0, stream>>>(off, part, N);
  fill_kernel<<<(E + 255) / 256, 256, 0, stream>>>(rows, cols, off, csr_src, E);

  // --- converts + weight packs ---
  cvt_kernel<<<(N * 128 / 4 + 255) / 256, 256, 0, stream>>>(x_self, S1, N * 32);
  pack_kernel<128, 128><<<8, 256, 0, stream>>>(Wis, pWis);
  pack_kernel<128, 128><<<8, 256, 0, stream>>>(Wg1, pWg1);
  pack_kernel<128, 64><<<4, 256, 0, stream>>>(Wos, pWos0);
  pack_kernel<128, 64><<<4, 256, 0, stream>>>(Wos + 128 * 64, pWos1);
  pack_kernel<128, 64><<<4, 256, 0, stream>>>(Wg2, pWg2);
  pack_kernel<128, 64><<<4, 256, 0, stream>>>(Wo, pWo0);
  pack_kernel<64, 64><<<2, 256, 0, stream>>>(Wo + 128 * 64, pWo1);

  const int GB = N / 64;  // 625 GEMM blocks

  // --- self branch ---
  // S2 = relu(x @ Wis + bis)
  mfma_gemm_kernel<128, 0, 128, true, true>
      <<<GB, 256, 0, stream>>>(S1, nullptr, pWis, nullptr, bis, S2);
  // out1 = x @ Wos0 + S2 @ Wos1 + bos
  mfma_gemm_kernel<128, 128, 64, false, false>
      <<<GB, 256, 0, stream>>>(S1, S2, pWos0, pWos1, bos, out1);

  // --- GCN branch ---
  // S2 = x @ Wg1  (bias folded into gather)
  mfma_gemm_kernel<128, 0, 128, false, true>
      <<<GB, 256, 0, stream>>>(S1, nullptr, pWg1, nullptr, nullptr, S2);
  // S1 = g1 = Agg(S2) + bg1
  gather128_kernel<<<(N + 3) / 4, 256, 0, stream>>>(S2, csr_src, off, dis, bg1,
                                                    S1, N);
  // S2 = g1 @ Wg2  [N,64]
  mfma_gemm_kernel<128, 0, 64, false, true>
      <<<GB, 256, 0, stream>>>(S1, nullptr, pWg2, nullptr, nullptr, S2);
  // S1 = g2 = Agg(S2) + bg2  [N,64]
  gather64_kernel<<<(N + 3) / 4, 256, 0, stream>>>(S2, csr_src, off, dis, bg2,
                                                   S1, N);
  // S2 = bf16(x_neighbor)
  cvt_kernel<<<(N * 128 / 4 + 255) / 256, 256, 0, stream>>>(x_nb, S2, N * 32);
  // out2 = x_nb @ Wo0 + g2 @ Wo1 + bo
  mfma_gemm_kernel<128, 64, 64, false, false>
      <<<GB, 256, 0, stream>>>(S2, S1, pWo0, pWo1, bo, out2);
}

// Round 6
// 182.122 us; speedup vs baseline: 3.6513x; 1.3603x over previous
//
#include <hip/hip_runtime.h>

typedef short s8v __attribute__((ext_vector_type(8)));
typedef float f4v __attribute__((ext_vector_type(4)));

__device__ __forceinline__ unsigned short f2bf(float f) {
  unsigned u = __float_as_uint(f);
  u = (u + 0x7fffu + ((u >> 16) & 1u)) >> 16;
  return (unsigned short)u;
}
__device__ __forceinline__ float bf2f(unsigned short s) {
  return __uint_as_float(((unsigned)s) << 16);
}
__device__ __forceinline__ float bflo(unsigned u) {
  return __uint_as_float(u << 16);
}
__device__ __forceinline__ float bfhi(unsigned u) {
  return __uint_as_float(u & 0xffff0000u);
}

// ---------------------------------------------------------------------------
// f32 -> bf16 convert, 4 elems/thread
// ---------------------------------------------------------------------------
__global__ __launch_bounds__(256) void cvt_kernel(
    const float* __restrict__ in, unsigned short* __restrict__ out, int n4) {
  const int i = blockIdx.x * 256 + threadIdx.x;
  if (i >= n4) return;
  const float4 v = reinterpret_cast<const float4*>(in)[i];
  ushort4 o;
  o.x = f2bf(v.x); o.y = f2bf(v.y); o.z = f2bf(v.z); o.w = f2bf(v.w);
  reinterpret_cast<ushort4*>(out)[i] = o;
}

// ---------------------------------------------------------------------------
// Pack all weights into MFMA B-fragment order in ONE dispatch.
// Fragment order: P[((kc*(NC/16)+ct)*64+lane)*8+j] =
//                 bf16( W[kc*32+(lane>>4)*8+j][ct*16+(lane&15)] )
// ---------------------------------------------------------------------------
__device__ __forceinline__ void pack_one(const float* __restrict__ W,
                                         unsigned short* __restrict__ P,
                                         int NC, int t) {
  const int lane = t & 63;
  const int ct = (t >> 6) % (NC / 16);
  const int kc = (t >> 6) / (NC / 16);
  const int col = ct * 16 + (lane & 15);
  const int krow = kc * 32 + (lane >> 4) * 8;
  unsigned short tmp[8];
#pragma unroll
  for (int j = 0; j < 8; ++j) tmp[j] = f2bf(W[(krow + j) * NC + col]);
  uint4 o;
  o.x = (unsigned)tmp[0] | ((unsigned)tmp[1] << 16);
  o.y = (unsigned)tmp[2] | ((unsigned)tmp[3] << 16);
  o.z = (unsigned)tmp[4] | ((unsigned)tmp[5] << 16);
  o.w = (unsigned)tmp[6] | ((unsigned)tmp[7] << 16);
  reinterpret_cast<uint4*>(P)[t] = o;
}

// 34 blocks: 8 Wis | 8 Wg1 | 4 Wos0 | 4 Wos1 | 4 Wg2 | 4 Wo0 | 2 Wo1
__global__ __launch_bounds__(256) void pack_all_kernel(
    const float* __restrict__ Wis, const float* __restrict__ Wos,
    const float* __restrict__ Wg1, const float* __restrict__ Wg2,
    const float* __restrict__ Wo, unsigned short* __restrict__ P) {
  const int b = blockIdx.x;
  const int tid = threadIdx.x;
  if (b < 8)        pack_one(Wis,            P + 0,     128, b * 256 + tid);
  else if (b < 16)  pack_one(Wg1,            P + 16384, 128, (b - 8) * 256 + tid);
  else if (b < 20)  pack_one(Wos,            P + 32768, 64,  (b - 16) * 256 + tid);
  else if (b < 24)  pack_one(Wos + 128 * 64, P + 40960, 64,  (b - 20) * 256 + tid);
  else if (b < 28)  pack_one(Wg2,            P + 49152, 64,  (b - 24) * 256 + tid);
  else if (b < 32)  pack_one(Wo,             P + 57344, 64,  (b - 28) * 256 + tid);
  else              pack_one(Wo + 128 * 64,  P + 65536, 64,  (b - 32) * 256 + tid);
}

// ---------------------------------------------------------------------------
// MFMA GEMM: C = A1[M x K1] @ B1 (+ A2[M x K2] @ B2) + bias, optional relu.
// A1 bf16 row-major, or f32 row-major if A1F32 (converted in-register).
// B* pre-packed fragment-order bf16 staged in LDS. M % 64 == 0.
// ---------------------------------------------------------------------------
template <int K1, int K2, int NC, bool RELU, bool OUT_BF16, bool A1F32>
__global__ __launch_bounds__(256) void mfma_gemm_kernel(
    const void* __restrict__ A1v, const unsigned short* __restrict__ A2,
    const unsigned short* __restrict__ P1, const unsigned short* __restrict__ P2,
    const float* __restrict__ bias, void* __restrict__ Cout) {
  constexpr int NT = NC / 16;
  constexpr int KC1 = K1 / 32;
  constexpr int KC2 = (K2 > 0) ? (K2 / 32) : 1;
  __shared__ unsigned short Bs[(K1 + K2) * NC];

  {
    uint4* d = reinterpret_cast<uint4*>(Bs);
    constexpr int n1 = K1 * NC / 8;
    const uint4* s1 = reinterpret_cast<const uint4*>(P1);
    for (int i = threadIdx.x; i < n1; i += 256) d[i] = s1[i];
    if constexpr (K2 > 0) {
      constexpr int n2 = K2 * NC / 8;
      const uint4* s2 = reinterpret_cast<const uint4*>(P2);
      for (int i = threadIdx.x; i < n2; i += 256) d[n1 + i] = s2[i];
    }
  }

  const int wave = threadIdx.x >> 6;
  const int lane = threadIdx.x & 63;
  const int row0 = blockIdx.x * 64 + wave * 16;
  const int arow = row0 + (lane & 15);
  const int koff = (lane >> 4) * 8;

  s8v a1[KC1];
  if constexpr (A1F32) {
    const float* A1f = (const float*)A1v;
#pragma unroll
    for (int kc = 0; kc < KC1; ++kc) {
      const float4 f0 = *reinterpret_cast<const float4*>(
          A1f + (long long)arow * K1 + kc * 32 + koff);
      const float4 f1 = *reinterpret_cast<const float4*>(
          A1f + (long long)arow * K1 + kc * 32 + koff + 4);
      s8v r;
      r[0] = (short)f2bf(f0.x); r[1] = (short)f2bf(f0.y);
      r[2] = (short)f2bf(f0.z); r[3] = (short)f2bf(f0.w);
      r[4] = (short)f2bf(f1.x); r[5] = (short)f2bf(f1.y);
      r[6] = (short)f2bf(f1.z); r[7] = (short)f2bf(f1.w);
      a1[kc] = r;
    }
  } else {
    const unsigned short* A1b = (const unsigned short*)A1v;
#pragma unroll
    for (int kc = 0; kc < KC1; ++kc)
      a1[kc] = *reinterpret_cast<const s8v*>(A1b + (long long)arow * K1 +
                                             kc * 32 + koff);
  }
  s8v a2[KC2];
  if constexpr (K2 > 0) {
#pragma unroll
    for (int kc = 0; kc < K2 / 32; ++kc)
      a2[kc] = *reinterpret_cast<const s8v*>(A2 + (long long)arow * K2 +
                                             kc * 32 + koff);
  }

  __syncthreads();

  f4v acc[NT] = {};
#pragma unroll
  for (int kc = 0; kc < KC1; ++kc) {
#pragma unroll
    for (int ct = 0; ct < NT; ++ct) {
      const s8v b =
          *reinterpret_cast<const s8v*>(&Bs[((kc * NT + ct) * 64 + lane) * 8]);
      acc[ct] = __builtin_amdgcn_mfma_f32_16x16x32_bf16(a1[kc], b, acc[ct], 0, 0, 0);
    }
  }
  if constexpr (K2 > 0) {
#pragma unroll
    for (int kc = 0; kc < K2 / 32; ++kc) {
#pragma unroll
      for (int ct = 0; ct < NT; ++ct) {
        const s8v b = *reinterpret_cast<const s8v*>(
            &Bs[(((KC1 + kc) * NT + ct) * 64 + lane) * 8]);
        acc[ct] = __builtin_amdgcn_mfma_f32_16x16x32_bf16(a2[kc], b, acc[ct], 0, 0, 0);
      }
    }
  }

  const int crow0 = row0 + (lane >> 4) * 4;
  const int ccol = lane & 15;
#pragma unroll
  for (int ct = 0; ct < NT; ++ct) {
    const int col = ct * 16 + ccol;
    const float bv = bias ? bias[col] : 0.f;
#pragma unroll
    for (int r = 0; r < 4; ++r) {
      float v = acc[ct][r] + bv;
      if (RELU) v = fmaxf(v, 0.f);
      const long long idx = (long long)(crow0 + r) * NC + col;
      if (OUT_BF16)
        ((unsigned short*)Cout)[idx] = f2bf(v);
      else
        ((float*)Cout)[idx] = v;
    }
  }
}

// ---------------------------------------------------------------------------
// CSR build
// ---------------------------------------------------------------------------
__global__ __launch_bounds__(256) void deg_kernel(
    const int* __restrict__ cols, int* __restrict__ deg, int E) {
  const int i = blockIdx.x * 256 + threadIdx.x;
  if (i < E) atomicAdd(&deg[cols[i]], 1);
}

// per-block inclusive->exclusive scan of deg into off, block sums into part,
// and dis[i] = rsqrt(deg[i]+1) fused in.
__global__ __launch_bounds__(1024) void scan1_kernel(
    const int* __restrict__ deg, int* __restrict__ off, int* __restrict__ part,
    float* __restrict__ dis, int N) {
  __shared__ int s[1024];
  const int tid = threadIdx.x;
  const int i = blockIdx.x * 1024 + tid;
  const int v = (i < N) ? deg[i] : 0;
  if (i < N) dis[i] = rsqrtf((float)v + 1.0f);
  s[tid] = v;
  __syncthreads();
  for (int o = 1; o < 1024; o <<= 1) {
    const int t = (tid >= o) ? s[tid - o] : 0;
    __syncthreads();
    s[tid] += t;
    __syncthreads();
  }
  if (i < N) off[i] = s[tid] - v;
  if (tid == 1023) part[blockIdx.x] = s[1023];
}

// adds prefix of part[] (computed per block via 64-lane shuffle reduce; NB<=64)
__global__ __launch_bounds__(1024) void scan3_kernel(
    int* __restrict__ off, const int* __restrict__ part, int N) {
  __shared__ int pp;
  if (threadIdx.x < 64) {
    int v = (threadIdx.x < blockIdx.x) ? part[threadIdx.x] : 0;
#pragma unroll
    for (int o = 32; o > 0; o >>= 1) v += __shfl_down(v, o, 64);
    if (threadIdx.x == 0) pp = v;
  }
  __syncthreads();
  const int i = blockIdx.x * 1024 + threadIdx.x;
  if (i < N) off[i] += pp;
}

// csr[pos] = (src, w = dis[src]*dis[dst]).  Afterwards off[c] = END of seg c.
__global__ __launch_bounds__(256) void fill_kernel(
    const int* __restrict__ rows, const int* __restrict__ cols,
    int* __restrict__ off, const float* __restrict__ dis,
    int2* __restrict__ csr, int E) {
  const int i = blockIdx.x * 256 + threadIdx.x;
  if (i < E) {
    const int c = cols[i];
    const int r = rows[i];
    const int pos = atomicAdd(&off[c], 1);
    int2 e;
    e.x = r;
    e.y = __float_as_int(dis[r] * dis[c]);
    csr[pos] = e;
  }
}

// ---------------------------------------------------------------------------
// CSR gathers: grid-stride waves over nodes, 4-deep unrolled edge loop.
// out[n] = sum_e h[src_e]*w_e + h[n]*dis[n]^2 + bias
// ---------------------------------------------------------------------------
__global__ __launch_bounds__(256) void gather128_kernel(
    const unsigned short* __restrict__ h, const int2* __restrict__ csr,
    const int* __restrict__ off, const float* __restrict__ dis,
    const float* __restrict__ bias, unsigned short* __restrict__ out, int N) {
  const int gw = (blockIdx.x * 256 + threadIdx.x) >> 6;
  const int lane = threadIdx.x & 63;
  const int nw = gridDim.x * 4;
  const unsigned* h32 = reinterpret_cast<const unsigned*>(h);
  unsigned* o32 = reinterpret_cast<unsigned*>(out);
  const float b0 = bias[lane * 2], b1 = bias[lane * 2 + 1];

  for (int n = gw; n < N; n += nw) {
    const float dn = dis[n];
    const unsigned us = h32[(long long)n * 64 + lane];
    float a0 = bflo(us) * (dn * dn);
    float a1 = bfhi(us) * (dn * dn);
    const int start = (n == 0) ? 0 : off[n - 1];
    const int end = off[n];
    int j = start;
    for (; j + 3 < end; j += 4) {
      const int2 p0 = csr[j], p1 = csr[j + 1], p2 = csr[j + 2], p3 = csr[j + 3];
      const unsigned u0 = h32[(long long)p0.x * 64 + lane];
      const unsigned u1 = h32[(long long)p1.x * 64 + lane];
      const unsigned u2 = h32[(long long)p2.x * 64 + lane];
      const unsigned u3 = h32[(long long)p3.x * 64 + lane];
      const float w0 = __int_as_float(p0.y), w1 = __int_as_float(p1.y);
      const float w2 = __int_as_float(p2.y), w3 = __int_as_float(p3.y);
      a0 = fmaf(bflo(u0), w0, a0); a1 = fmaf(bfhi(u0), w0, a1);
      a0 = fmaf(bflo(u1), w1, a0); a1 = fmaf(bfhi(u1), w1, a1);
      a0 = fmaf(bflo(u2), w2, a0); a1 = fmaf(bfhi(u2), w2, a1);
      a0 = fmaf(bflo(u3), w3, a0); a1 = fmaf(bfhi(u3), w3, a1);
    }
    for (; j < end; ++j) {
      const int2 p = csr[j];
      const unsigned u = h32[(long long)p.x * 64 + lane];
      const float w = __int_as_float(p.y);
      a0 = fmaf(bflo(u), w, a0);
      a1 = fmaf(bfhi(u), w, a1);
    }
    o32[(long long)n * 64 + lane] =
        (unsigned)f2bf(a0 + b0) | ((unsigned)f2bf(a1 + b1) << 16);
  }
}

__global__ __launch_bounds__(256) void gather64_kernel(
    const unsigned short* __restrict__ h, const int2* __restrict__ csr,
    const int* __restrict__ off, const float* __restrict__ dis,
    const float* __restrict__ bias, unsigned short* __restrict__ out, int N) {
  const int gw = (blockIdx.x * 256 + threadIdx.x) >> 6;
  const int lane = threadIdx.x & 63;
  const int nw = gridDim.x * 4;
  const float bb = bias[lane];

  for (int n = gw; n < N; n += nw) {
    const float dn = dis[n];
    float a0 = bf2f(h[(long long)n * 64 + lane]) * (dn * dn);
    const int start = (n == 0) ? 0 : off[n - 1];
    const int end = off[n];
    int j = start;
    for (; j + 3 < end; j += 4) {
      const int2 p0 = csr[j], p1 = csr[j + 1], p2 = csr[j + 2], p3 = csr[j + 3];
      const float v0 = bf2f(h[(long long)p0.x * 64 + lane]);
      const float v1 = bf2f(h[(long long)p1.x * 64 + lane]);
      const float v2 = bf2f(h[(long long)p2.x * 64 + lane]);
      const float v3 = bf2f(h[(long long)p3.x * 64 + lane]);
      a0 = fmaf(v0, __int_as_float(p0.y), a0);
      a0 = fmaf(v1, __int_as_float(p1.y), a0);
      a0 = fmaf(v2, __int_as_float(p2.y), a0);
      a0 = fmaf(v3, __int_as_float(p3.y), a0);
    }
    for (; j < end; ++j) {
      const int2 p = csr[j];
      a0 = fmaf(bf2f(h[(long long)p.x * 64 + lane]), __int_as_float(p.y), a0);
    }
    out[(long long)n * 64 + lane] = f2bf(a0 + bb);
  }
}

extern "C" void kernel_launch(void* const* d_in, const int* in_sizes, int n_in,
                              void* d_out, int out_size, void* d_ws,
                              size_t ws_size, hipStream_t stream) {
  const float* x_self = (const float*)d_in[0];
  const float* x_nb = (const float*)d_in[1];
  const int* ei = (const int*)d_in[2];
  const float* Wis = (const float*)d_in[3];
  const float* bis = (const float*)d_in[4];
  const float* Wos = (const float*)d_in[5];
  const float* bos = (const float*)d_in[6];
  const float* Wg1 = (const float*)d_in[7];
  const float* bg1 = (const float*)d_in[8];
  const float* Wg2 = (const float*)d_in[9];
  const float* bg2 = (const float*)d_in[10];
  const float* Wo = (const float*)d_in[11];
  const float* bo = (const float*)d_in[12];

  const int N = in_sizes[0] / 128;
  const int E = (int)(in_sizes[2] / 2);
  const int* rows = ei;
  const int* cols = ei + E;

  float* out1 = (float*)d_out;
  float* out2 = out1 + (long long)N * 64;

  // ws (4B units): dis[N] | deg[N] | off[N+16] | part[64] | csr int2[E] |
  //                S1 bf16[N*128] | S2 bf16[N*128] | P bf16[69632]
  float* dis = (float*)d_ws;
  int* deg = (int*)(dis + N);
  int* off = deg + N;
  int* part = off + N + 16;
  int2* csr = (int2*)(part + 64);
  unsigned short* S1 = (unsigned short*)(csr + E);
  unsigned short* S2 = S1 + (long long)N * 128;
  unsigned short* P = S2 + (long long)N * 128;
  unsigned short* pWis = P + 0;
  unsigned short* pWg1 = P + 16384;
  unsigned short* pWos0 = P + 32768;
  unsigned short* pWos1 = P + 40960;
  unsigned short* pWg2 = P + 49152;
  unsigned short* pWo0 = P + 57344;
  unsigned short* pWo1 = P + 65536;

  const int NB = (N + 1023) / 1024;
  const int GB = N / 64;       // 625
  const int GGB = 2048;        // gather blocks (8192 waves)

  // --- CSR build + norms ---
  hipMemsetAsync(deg, 0, (size_t)N * sizeof(int), stream);
  deg_kernel<<<(E + 255) / 256, 256, 0, stream>>>(cols, deg, E);
  scan1_kernel<<<NB, 1024, 0, stream>>>(deg, off, part, dis, N);
  scan3_kernel<<<NB, 1024, 0, stream>>>(off, part, N);
  fill_kernel<<<(E + 255) / 256, 256, 0, stream>>>(rows, cols, off, dis, csr, E);

  // --- conversions + packs ---
  cvt_kernel<<<(N * 32 + 255) / 256, 256, 0, stream>>>(x_self, S1, N * 32);
  pack_all_kernel<<<34, 256, 0, stream>>>(Wis, Wos, Wg1, Wg2, Wo, P);

  // --- self branch ---
  mfma_gemm_kernel<128, 0, 128, true, true, false>
      <<<GB, 256, 0, stream>>>(S1, nullptr, pWis, nullptr, bis, S2);
  mfma_gemm_kernel<128, 128, 64, false, false, false>
      <<<GB, 256, 0, stream>>>(S1, S2, pWos0, pWos1, bos, out1);

  // --- GCN branch ---
  mfma_gemm_kernel<128, 0, 128, false, true, false>
      <<<GB, 256, 0, stream>>>(S1, nullptr, pWg1, nullptr, nullptr, S2);
  gather128_kernel<<<GGB, 256, 0, stream>>>(S2, csr, off, dis, bg1, S1, N);
  mfma_gemm_kernel<128, 0, 64, false, true, false>
      <<<GB, 256, 0, stream>>>(S1, nullptr, pWg2, nullptr, nullptr, S2);
  gather64_kernel<<<GGB, 256, 0, stream>>>(S2, csr, off, dis, bg2, S1, N);
  mfma_gemm_kernel<128, 64, 64, false, false, true>
      <<<GB, 256, 0, stream>>>(x_nb, S1, pWo0, pWo1, bo, out2);
}

// Round 7
// 176.568 us; speedup vs baseline: 3.7661x; 1.0315x over previous
//
#include <hip/hip_runtime.h>

typedef short s8v __attribute__((ext_vector_type(8)));
typedef float f4v __attribute__((ext_vector_type(4)));

__device__ __forceinline__ unsigned short f2bf(float f) {
  unsigned u = __float_as_uint(f);
  u = (u + 0x7fffu + ((u >> 16) & 1u)) >> 16;
  return (unsigned short)u;
}
__device__ __forceinline__ float bf2f(unsigned short s) {
  return __uint_as_float(((unsigned)s) << 16);
}

// ---------------------------------------------------------------------------
__global__ __launch_bounds__(256) void zero_kernel(int* __restrict__ p, int n) {
  const int i = blockIdx.x * 256 + threadIdx.x;
  if (i < n) p[i] = 0;
}

// f32 -> bf16, 4 elems/thread
__global__ __launch_bounds__(256) void cvt_kernel(
    const float* __restrict__ in, unsigned short* __restrict__ out, int n4) {
  const int i = blockIdx.x * 256 + threadIdx.x;
  if (i >= n4) return;
  const float4 v = reinterpret_cast<const float4*>(in)[i];
  ushort4 o;
  o.x = f2bf(v.x); o.y = f2bf(v.y); o.z = f2bf(v.z); o.w = f2bf(v.w);
  reinterpret_cast<ushort4*>(out)[i] = o;
}

// ---------------------------------------------------------------------------
// W12f = Wg1(128x128) @ Wg2(128x64) in f32; bvec = bg1 @ Wg2.
// 33 blocks x 256 threads; one output element per thread.
// ---------------------------------------------------------------------------
__global__ __launch_bounds__(256) void w12_kernel(
    const float* __restrict__ W1, const float* __restrict__ W2,
    const float* __restrict__ b1, float* __restrict__ W12f,
    float* __restrict__ bvec) {
  const int b = blockIdx.x;
  if (b < 32) {
    const int t = b * 256 + threadIdx.x;  // t = i*64 + j
    const int i = t >> 6, j = t & 63;
    float acc = 0.f;
    for (int k = 0; k < 128; ++k)
      acc = fmaf(W1[i * 128 + k], W2[k * 64 + j], acc);
    W12f[t] = acc;
  } else if (threadIdx.x < 64) {
    const int j = threadIdx.x;
    float acc = 0.f;
    for (int k = 0; k < 128; ++k) acc = fmaf(b1[k], W2[k * 64 + j], acc);
    bvec[j] = acc;
  }
}

// ---------------------------------------------------------------------------
// Pack weights into MFMA B-fragment order:
// P[((kc*(NC/16)+ct)*64+lane)*8+j] = bf16( W[kc*32+(lane>>4)*8+j][ct*16+(lane&15)] )
// ---------------------------------------------------------------------------
__device__ __forceinline__ void pack_one(const float* __restrict__ W,
                                         unsigned short* __restrict__ P,
                                         int NC, int t) {
  const int lane = t & 63;
  const int ct = (t >> 6) % (NC / 16);
  const int kc = (t >> 6) / (NC / 16);
  const int col = ct * 16 + (lane & 15);
  const int krow = kc * 32 + (lane >> 4) * 8;
  unsigned short tmp[8];
#pragma unroll
  for (int j = 0; j < 8; ++j) tmp[j] = f2bf(W[(krow + j) * NC + col]);
  uint4 o;
  o.x = (unsigned)tmp[0] | ((unsigned)tmp[1] << 16);
  o.y = (unsigned)tmp[2] | ((unsigned)tmp[3] << 16);
  o.z = (unsigned)tmp[4] | ((unsigned)tmp[5] << 16);
  o.w = (unsigned)tmp[6] | ((unsigned)tmp[7] << 16);
  reinterpret_cast<uint4*>(P)[t] = o;
}

// 26 blocks: 8 Wis | 4 Wos0 | 4 Wos1 | 4 Wo0 | 2 Wo1 | 4 W12
__global__ __launch_bounds__(256) void pack_all_kernel(
    const float* __restrict__ Wis, const float* __restrict__ Wos,
    const float* __restrict__ Wo, const float* __restrict__ W12f,
    unsigned short* __restrict__ P) {
  const int b = blockIdx.x;
  const int tid = threadIdx.x;
  if (b < 8)        pack_one(Wis,            P + 0,     128, b * 256 + tid);
  else if (b < 12)  pack_one(Wos,            P + 16384, 64,  (b - 8) * 256 + tid);
  else if (b < 16)  pack_one(Wos + 128 * 64, P + 24576, 64,  (b - 12) * 256 + tid);
  else if (b < 20)  pack_one(Wo,             P + 32768, 64,  (b - 16) * 256 + tid);
  else if (b < 22)  pack_one(Wo + 128 * 64,  P + 40960, 64,  (b - 20) * 256 + tid);
  else              pack_one(W12f,           P + 45056, 64,  (b - 22) * 256 + tid);
}

// ---------------------------------------------------------------------------
// MFMA GEMM: C = A1[M x K1] @ B1 (+ A2[M x K2] @ B2) + bias, optional relu.
// A1 bf16 row-major, or f32 row-major if A1F32 (converted in-register).
// B* pre-packed fragment-order bf16 staged in LDS. M % 64 == 0.
// ---------------------------------------------------------------------------
template <int K1, int K2, int NC, bool RELU, bool OUT_BF16, bool A1F32>
__global__ __launch_bounds__(256) void mfma_gemm_kernel(
    const void* __restrict__ A1v, const unsigned short* __restrict__ A2,
    const unsigned short* __restrict__ P1, const unsigned short* __restrict__ P2,
    const float* __restrict__ bias, void* __restrict__ Cout) {
  constexpr int NT = NC / 16;
  constexpr int KC1 = K1 / 32;
  constexpr int KC2 = (K2 > 0) ? (K2 / 32) : 1;
  __shared__ unsigned short Bs[(K1 + K2) * NC];

  {
    uint4* d = reinterpret_cast<uint4*>(Bs);
    constexpr int n1 = K1 * NC / 8;
    const uint4* s1 = reinterpret_cast<const uint4*>(P1);
    for (int i = threadIdx.x; i < n1; i += 256) d[i] = s1[i];
    if constexpr (K2 > 0) {
      constexpr int n2 = K2 * NC / 8;
      const uint4* s2 = reinterpret_cast<const uint4*>(P2);
      for (int i = threadIdx.x; i < n2; i += 256) d[n1 + i] = s2[i];
    }
  }

  const int wave = threadIdx.x >> 6;
  const int lane = threadIdx.x & 63;
  const int row0 = blockIdx.x * 64 + wave * 16;
  const int arow = row0 + (lane & 15);
  const int koff = (lane >> 4) * 8;

  s8v a1[KC1];
  if constexpr (A1F32) {
    const float* A1f = (const float*)A1v;
#pragma unroll
    for (int kc = 0; kc < KC1; ++kc) {
      const float4 f0 = *reinterpret_cast<const float4*>(
          A1f + (long long)arow * K1 + kc * 32 + koff);
      const float4 f1 = *reinterpret_cast<const float4*>(
          A1f + (long long)arow * K1 + kc * 32 + koff + 4);
      s8v r;
      r[0] = (short)f2bf(f0.x); r[1] = (short)f2bf(f0.y);
      r[2] = (short)f2bf(f0.z); r[3] = (short)f2bf(f0.w);
      r[4] = (short)f2bf(f1.x); r[5] = (short)f2bf(f1.y);
      r[6] = (short)f2bf(f1.z); r[7] = (short)f2bf(f1.w);
      a1[kc] = r;
    }
  } else {
    const unsigned short* A1b = (const unsigned short*)A1v;
#pragma unroll
    for (int kc = 0; kc < KC1; ++kc)
      a1[kc] = *reinterpret_cast<const s8v*>(A1b + (long long)arow * K1 +
                                             kc * 32 + koff);
  }
  s8v a2[KC2];
  if constexpr (K2 > 0) {
#pragma unroll
    for (int kc = 0; kc < K2 / 32; ++kc)
      a2[kc] = *reinterpret_cast<const s8v*>(A2 + (long long)arow * K2 +
                                             kc * 32 + koff);
  }

  __syncthreads();

  f4v acc[NT] = {};
#pragma unroll
  for (int kc = 0; kc < KC1; ++kc) {
#pragma unroll
    for (int ct = 0; ct < NT; ++ct) {
      const s8v b =
          *reinterpret_cast<const s8v*>(&Bs[((kc * NT + ct) * 64 + lane) * 8]);
      acc[ct] = __builtin_amdgcn_mfma_f32_16x16x32_bf16(a1[kc], b, acc[ct], 0, 0, 0);
    }
  }
  if constexpr (K2 > 0) {
#pragma unroll
    for (int kc = 0; kc < K2 / 32; ++kc) {
#pragma unroll
      for (int ct = 0; ct < NT; ++ct) {
        const s8v b = *reinterpret_cast<const s8v*>(
            &Bs[(((KC1 + kc) * NT + ct) * 64 + lane) * 8]);
        acc[ct] = __builtin_amdgcn_mfma_f32_16x16x32_bf16(a2[kc], b, acc[ct], 0, 0, 0);
      }
    }
  }

  const int crow0 = row0 + (lane >> 4) * 4;
  const int ccol = lane & 15;
#pragma unroll
  for (int ct = 0; ct < NT; ++ct) {
    const int col = ct * 16 + ccol;
    const float bv = bias ? bias[col] : 0.f;
#pragma unroll
    for (int r = 0; r < 4; ++r) {
      float v = acc[ct][r] + bv;
      if (RELU) v = fmaxf(v, 0.f);
      const long long idx = (long long)(crow0 + r) * NC + col;
      if (OUT_BF16)
        ((unsigned short*)Cout)[idx] = f2bf(v);
      else
        ((float*)Cout)[idx] = v;
    }
  }
}

// ---------------------------------------------------------------------------
// CSR build
// ---------------------------------------------------------------------------
__global__ __launch_bounds__(256) void deg_kernel(
    const int* __restrict__ cols, int* __restrict__ deg, int E) {
  const int i = blockIdx.x * 256 + threadIdx.x;
  if (i < E) atomicAdd(&deg[cols[i]], 1);
}

__global__ __launch_bounds__(1024) void scan1_kernel(
    const int* __restrict__ deg, int* __restrict__ off, int* __restrict__ part,
    float* __restrict__ dis, int N) {
  __shared__ int s[1024];
  const int tid = threadIdx.x;
  const int i = blockIdx.x * 1024 + tid;
  const int v = (i < N) ? deg[i] : 0;
  if (i < N) dis[i] = rsqrtf((float)v + 1.0f);
  s[tid] = v;
  __syncthreads();
  for (int o = 1; o < 1024; o <<= 1) {
    const int t = (tid >= o) ? s[tid - o] : 0;
    __syncthreads();
    s[tid] += t;
    __syncthreads();
  }
  if (i < N) off[i] = s[tid] - v;
  if (tid == 1023) part[blockIdx.x] = s[1023];
}

__global__ __launch_bounds__(1024) void scan3_kernel(
    int* __restrict__ off, const int* __restrict__ part, int N) {
  __shared__ int pp;
  if (threadIdx.x < 64) {
    int v = (threadIdx.x < blockIdx.x) ? part[threadIdx.x] : 0;
#pragma unroll
    for (int o = 32; o > 0; o >>= 1) v += __shfl_down(v, o, 64);
    if (threadIdx.x == 0) pp = v;
  }
  __syncthreads();
  const int i = blockIdx.x * 1024 + threadIdx.x;
  if (i < N) off[i] += pp;
}

// csr[pos] = (src, w = dis[src]*dis[dst]).  Afterwards off[c] = END of seg c.
__global__ __launch_bounds__(256) void fill_kernel(
    const int* __restrict__ rows, const int* __restrict__ cols,
    int* __restrict__ off, const float* __restrict__ dis,
    int2* __restrict__ csr, int E) {
  const int i = blockIdx.x * 256 + threadIdx.x;
  if (i < E) {
    const int c = cols[i];
    const int r = rows[i];
    const int pos = atomicAdd(&off[c], 1);
    int2 e;
    e.x = r;
    e.y = __float_as_int(dis[r] * dis[c]);
    csr[pos] = e;
  }
}

// ---------------------------------------------------------------------------
// D=64 CSR gather, grid-stride waves, 4-deep unroll.
// Pass A: out[n]=A·h (bf16), s_out[n]=Σw+dn² (row-sum of A).
// Pass B: out[n]=A·h + s_in[n]*bvec + bias (bf16).
// ---------------------------------------------------------------------------
template <bool PASS_B>
__global__ __launch_bounds__(256) void gather64_kernel(
    const unsigned short* __restrict__ h, const int2* __restrict__ csr,
    const int* __restrict__ off, const float* __restrict__ dis,
    float* __restrict__ s_out, const float* __restrict__ s_in,
    const float* __restrict__ bvec, const float* __restrict__ bias,
    unsigned short* __restrict__ out, int N) {
  const int gw = (blockIdx.x * 256 + threadIdx.x) >> 6;
  const int lane = threadIdx.x & 63;
  const int nw = gridDim.x * 4;
  const float bb = PASS_B ? bias[lane] : 0.f;
  const float bvl = PASS_B ? bvec[lane] : 0.f;

  for (int n = gw; n < N; n += nw) {
    const float dn = dis[n];
    const float dn2 = dn * dn;
    float a0 = bf2f(h[(long long)n * 64 + lane]) * dn2;
    float sw = dn2;
    const int start = (n == 0) ? 0 : off[n - 1];
    const int end = off[n];
    int j = start;
    for (; j + 3 < end; j += 4) {
      const int2 p0 = csr[j], p1 = csr[j + 1], p2 = csr[j + 2], p3 = csr[j + 3];
      const float v0 = bf2f(h[(long long)p0.x * 64 + lane]);
      const float v1 = bf2f(h[(long long)p1.x * 64 + lane]);
      const float v2 = bf2f(h[(long long)p2.x * 64 + lane]);
      const float v3 = bf2f(h[(long long)p3.x * 64 + lane]);
      const float w0 = __int_as_float(p0.y), w1 = __int_as_float(p1.y);
      const float w2 = __int_as_float(p2.y), w3 = __int_as_float(p3.y);
      a0 = fmaf(v0, w0, a0);
      a0 = fmaf(v1, w1, a0);
      a0 = fmaf(v2, w2, a0);
      a0 = fmaf(v3, w3, a0);
      if constexpr (!PASS_B) sw += (w0 + w1) + (w2 + w3);
    }
    for (; j < end; ++j) {
      const int2 p = csr[j];
      a0 = fmaf(bf2f(h[(long long)p.x * 64 + lane]), __int_as_float(p.y), a0);
      if constexpr (!PASS_B) sw += __int_as_float(p.y);
    }
    if constexpr (!PASS_B) {
      if (lane == 0) s_out[n] = sw;
      out[(long long)n * 64 + lane] = f2bf(a0);
    } else {
      out[(long long)n * 64 + lane] = f2bf(fmaf(s_in[n], bvl, a0 + bb));
    }
  }
}

extern "C" void kernel_launch(void* const* d_in, const int* in_sizes, int n_in,
                              void* d_out, int out_size, void* d_ws,
                              size_t ws_size, hipStream_t stream) {
  const float* x_self = (const float*)d_in[0];
  const float* x_nb = (const float*)d_in[1];
  const int* ei = (const int*)d_in[2];
  const float* Wis = (const float*)d_in[3];
  const float* bis = (const float*)d_in[4];
  const float* Wos = (const float*)d_in[5];
  const float* bos = (const float*)d_in[6];
  const float* Wg1 = (const float*)d_in[7];
  const float* bg1 = (const float*)d_in[8];
  const float* Wg2 = (const float*)d_in[9];
  const float* bg2 = (const float*)d_in[10];
  const float* Wo = (const float*)d_in[11];
  const float* bo = (const float*)d_in[12];

  const int N = in_sizes[0] / 128;
  const int E = (int)(in_sizes[2] / 2);
  const int* rows = ei;
  const int* cols = ei + E;

  float* out1 = (float*)d_out;
  float* out2 = out1 + (long long)N * 64;

  // ws (4B units): dis[N] | deg[N] | off[N+16] | part[64] | s[N] |
  //   W12f[8192] | bvec[64] | csr int2[E] | S1 bf16[N*128] | S2 bf16[N*128] |
  //   S3 bf16[N*64] | P bf16[53248]
  float* dis = (float*)d_ws;
  int* deg = (int*)(dis + N);
  int* off = deg + N;
  int* part = off + N + 16;
  float* s = (float*)(part + 64);
  float* W12f = s + N;
  float* bvec = W12f + 8192;
  int2* csr = (int2*)(bvec + 64);
  unsigned short* S1 = (unsigned short*)(csr + E);
  unsigned short* S2 = S1 + (long long)N * 128;
  unsigned short* S3 = S2 + (long long)N * 128;
  unsigned short* P = S3 + (long long)N * 64;
  unsigned short* pWis = P + 0;
  unsigned short* pWos0 = P + 16384;
  unsigned short* pWos1 = P + 24576;
  unsigned short* pWo0 = P + 32768;
  unsigned short* pWo1 = P + 40960;
  unsigned short* pW12 = P + 45056;

  const int NB = (N + 1023) / 1024;
  const int GB = N / 64;   // 625
  const int GGB = 2048;    // gather blocks

  // --- CSR build + norms (no hipMemset: custom zero) ---
  zero_kernel<<<(N + 255) / 256, 256, 0, stream>>>(deg, N);
  deg_kernel<<<(E + 255) / 256, 256, 0, stream>>>(cols, deg, E);
  scan1_kernel<<<NB, 1024, 0, stream>>>(deg, off, part, dis, N);
  scan3_kernel<<<NB, 1024, 0, stream>>>(off, part, N);
  fill_kernel<<<(E + 255) / 256, 256, 0, stream>>>(rows, cols, off, dis, csr, E);

  // --- conversions + weight prep ---
  cvt_kernel<<<(N * 32 + 255) / 256, 256, 0, stream>>>(x_self, S1, N * 32);
  w12_kernel<<<33, 256, 0, stream>>>(Wg1, Wg2, bg1, W12f, bvec);
  pack_all_kernel<<<26, 256, 0, stream>>>(Wis, Wos, Wo, W12f, P);

  // --- self branch ---
  mfma_gemm_kernel<128, 0, 128, true, true, false>
      <<<GB, 256, 0, stream>>>(S1, nullptr, pWis, nullptr, bis, S2);
  mfma_gemm_kernel<128, 128, 64, false, false, false>
      <<<GB, 256, 0, stream>>>(S1, S2, pWos0, pWos1, bos, out1);

  // --- GCN branch: g2 = A·(A·(X·W12)) + s·(bg1·Wg2) + bg2 ---
  mfma_gemm_kernel<128, 0, 64, false, true, false>
      <<<GB, 256, 0, stream>>>(S1, nullptr, pW12, nullptr, nullptr, S2);
  gather64_kernel<false><<<GGB, 256, 0, stream>>>(
      S2, csr, off, dis, s, nullptr, nullptr, nullptr, S3, N);
  gather64_kernel<true><<<GGB, 256, 0, stream>>>(
      S3, csr, off, dis, nullptr, s, bvec, bg2, S1, N);
  mfma_gemm_kernel<128, 64, 64, false, false, true>
      <<<GB, 256, 0, stream>>>(x_nb, S1, pWo0, pWo1, bo, out2);
}